// Round 1
// baseline (750.982 us; speedup 1.0000x reference)
//
#include <hip/hip_runtime.h>
#include <hip/hip_bf16.h>
#include <math.h>

#define Bn 128
#define Sn 128
#define Hn 1024
#define Vn 50000

using short8  = __attribute__((ext_vector_type(8))) short;
using floatx4 = __attribute__((ext_vector_type(4))) float;

__device__ __forceinline__ unsigned short f2bf_bits(float f) {
  union { __hip_bfloat16 h; unsigned short u; } cv;
  cv.h = __float2bfloat16(f);
  return cv.u;
}
__device__ __forceinline__ float bf_bits2f(unsigned short u) {
  union { __hip_bfloat16 h; unsigned short u; } cv;
  cv.u = u;
  return __bfloat162float(cv.h);
}
__device__ __forceinline__ short8 cvt8(float4 a, float4 b) {
  short8 r;
  r[0]=(short)f2bf_bits(a.x); r[1]=(short)f2bf_bits(a.y);
  r[2]=(short)f2bf_bits(a.z); r[3]=(short)f2bf_bits(a.w);
  r[4]=(short)f2bf_bits(b.x); r[5]=(short)f2bf_bits(b.y);
  r[6]=(short)f2bf_bits(b.z); r[7]=(short)f2bf_bits(b.w);
  return r;
}
__device__ __forceinline__ void split8(float4 a, float4 b, short8& hi, short8& lo) {
  float f[8] = {a.x,a.y,a.z,a.w,b.x,b.y,b.z,b.w};
#pragma unroll
  for (int i=0;i<8;++i) {
    unsigned short h = f2bf_bits(f[i]);
    hi[i] = (short)h;
    lo[i] = (short)f2bf_bits(f[i] - bf_bits2f(h));
  }
}
__device__ __forceinline__ floatx4 mfma16(short8 a, short8 b, floatx4 c) {
  return __builtin_amdgcn_mfma_f32_16x16x32_bf16(a, b, c, 0, 0, 0);
}

// K1: pack A matrix for LSTM GEMM: xh_hi[b][0:1024]=bf16(emb[input[b]]),
// xh_hi[b][1024:2048]=bf16(prev_h), xh_lo[b][0:1024]=bf16(prev_h - hi(prev_h))
__global__ void __launch_bounds__(256) k1_pack(const int* __restrict__ inp,
    const float* __restrict__ prev_h, const float* __restrict__ emb,
    unsigned short* __restrict__ xh_hi, unsigned short* __restrict__ xh_lo) {
  int idx = blockIdx.x*256 + threadIdx.x;       // 0..262143
  int b = idx >> 11, k = idx & 2047;
  if (k < 1024) {
    float v = emb[(size_t)inp[b]*Hn + k];
    xh_hi[idx] = f2bf_bits(v);
  } else {
    float v = prev_h[b*Hn + (k-1024)];
    unsigned short hi = f2bf_bits(v);
    xh_hi[idx] = hi;
    xh_lo[b*Hn + (k-1024)] = f2bf_bits(v - bf_bits2f(hi));
  }
}

// K2: gates[128][4096] = x@W_ih^T + prev_h@W_hh^T + b_ih + b_hh (split-bf16 on h-part)
__global__ void __launch_bounds__(64) k2_gates(
    const unsigned short* __restrict__ xh_hi, const unsigned short* __restrict__ xh_lo,
    const float* __restrict__ W_ih, const float* __restrict__ W_hh,
    const float* __restrict__ b_ih, const float* __restrict__ b_hh,
    float* __restrict__ gates) {
  int lane = threadIdx.x, l15 = lane & 15, quad = lane >> 4;
  int n = blockIdx.x*16 + l15;
  floatx4 z = {0.f,0.f,0.f,0.f};
  floatx4 acc[8];
#pragma unroll
  for (int t=0;t<8;++t) acc[t] = z;

  // half 0: x @ W_ih^T, plain bf16
  for (int k0 = 0; k0 < 1024; k0 += 32) {
    int k = k0 + quad*8;
    const float* wp = W_ih + (size_t)n*Hn + k;
    float4 w0 = *(const float4*)wp;
    float4 w1 = *(const float4*)(wp+4);
    short8 bfrag = cvt8(w0,w1);
#pragma unroll
    for (int t=0;t<8;++t) {
      short8 afrag = *(const short8*)(xh_hi + (t*16 + l15)*2048 + k);
      acc[t] = mfma16(afrag, bfrag, acc[t]);
    }
  }
  // half 1: prev_h @ W_hh^T, split hi/lo for near-fp32 accuracy
  for (int k0 = 0; k0 < 1024; k0 += 32) {
    int k = k0 + quad*8;
    const float* wp = W_hh + (size_t)n*Hn + k;
    float4 w0 = *(const float4*)wp;
    float4 w1 = *(const float4*)(wp+4);
    short8 whi, wlo; split8(w0,w1,whi,wlo);
#pragma unroll
    for (int t=0;t<8;++t) {
      short8 ahi = *(const short8*)(xh_hi + (t*16 + l15)*2048 + 1024 + k);
      short8 alo = *(const short8*)(xh_lo + (t*16 + l15)*1024 + k);
      acc[t] = mfma16(ahi, whi, acc[t]);
      acc[t] = mfma16(alo, whi, acc[t]);
      acc[t] = mfma16(ahi, wlo, acc[t]);
    }
  }
  float bias = b_ih[n] + b_hh[n];
#pragma unroll
  for (int t=0;t<8;++t)
#pragma unroll
    for (int r=0;r<4;++r) {
      int m = t*16 + quad*4 + r;
      gates[m*4096 + n] = acc[t][r] + bias;
    }
}

// K3: LSTM elementwise -> h,c outputs + h fp32 + h bf16 into ctxh[:,1024:2048]
__global__ void __launch_bounds__(256) k3_lstm(const float* __restrict__ gates,
    const float* __restrict__ prev_c, float* __restrict__ out,
    float* __restrict__ h32, unsigned short* __restrict__ ctxh) {
  int idx = blockIdx.x*256 + threadIdx.x;       // 0..131071
  int b = idx >> 10, k = idx & 1023;
  const float* g = gates + b*4096;
  float gi = g[k], gf = g[k+1024], gg = g[k+2048], go = g[k+3072];
  float si = 1.f/(1.f+expf(-gi));
  float sf = 1.f/(1.f+expf(-gf));
  float so = 1.f/(1.f+expf(-go));
  float c = sf*prev_c[idx] + si*tanhf(gg);
  float h = so*tanhf(c);
  out[6400000 + idx] = h;
  out[6531072 + idx] = c;
  h32[idx] = h;
  ctxh[b*2048 + 1024 + k] = f2bf_bits(h);
}

// K4a: scores[b][s] = dot(enc[b][s], h[b]); ==0 -> -1e11
__global__ void __launch_bounds__(256) k4a_scores(const float* __restrict__ enc,
    const float* __restrict__ h32, float* __restrict__ scores) {
  int w = blockIdx.x*4 + (threadIdx.x>>6);
  int lane = threadIdx.x & 63;
  int b = w >> 7, s = w & 127;
  const float* e = enc + (size_t)(b*Sn + s)*Hn;
  const float* hp = h32 + b*Hn;
  float sum = 0.f;
#pragma unroll
  for (int j=0;j<4;++j) {
    int k = j*256 + lane*4;
    float4 ev = *(const float4*)(e+k);
    float4 hv = *(const float4*)(hp+k);
    sum += ev.x*hv.x + ev.y*hv.y + ev.z*hv.z + ev.w*hv.w;
  }
#pragma unroll
  for (int o=32;o>0;o>>=1) sum += __shfl_xor(sum, o, 64);
  if (lane==0) {
    if (sum == 0.f) sum = -1e11f;
    scores[b*Sn+s] = sum;
  }
}

// K4b: softmax over S (redundantly per h-chunk block) + context accumulate -> ctxh[:,0:1024] bf16
__global__ void __launch_bounds__(256) k4b_ctx(const float* __restrict__ enc,
    const float* __restrict__ scores, unsigned short* __restrict__ ctxh) {
  __shared__ float sc[128];
  __shared__ float red[128];
  int tid = threadIdx.x, b = blockIdx.y;
  if (tid < 128) { float v = scores[b*Sn+tid]; sc[tid] = v; red[tid] = v; }
  __syncthreads();
  for (int st=64; st>0; st>>=1) {
    if (tid<st) red[tid] = fmaxf(red[tid], red[tid+st]);
    __syncthreads();
  }
  float mx = red[0];
  __syncthreads();
  if (tid<128) { float e = expf(sc[tid]-mx); sc[tid]=e; red[tid]=e; }
  __syncthreads();
  for (int st=64; st>0; st>>=1) {
    if (tid<st) red[tid] += red[tid+st];
    __syncthreads();
  }
  float inv = 1.0f/red[0];
  __syncthreads();
  if (tid<128) sc[tid] *= inv;
  __syncthreads();
  int hcol = blockIdx.x*256 + tid;
  const float* e = enc + (size_t)b*(Sn*Hn) + hcol;
  float acc = 0.f;
#pragma unroll 8
  for (int s2=0; s2<128; ++s2) acc += sc[s2]*e[(size_t)s2*Hn];
  ctxh[b*2048 + hcol] = f2bf_bits(acc);
}

// K5: av = tanh([ctx,h] @ W_out^T + b_out) -> bf16 [128][1024]
__global__ void __launch_bounds__(64) k5_att(const unsigned short* __restrict__ ctxh,
    const float* __restrict__ W_out, const float* __restrict__ b_out,
    unsigned short* __restrict__ av) {
  int lane = threadIdx.x, l15 = lane&15, quad = lane>>6 ? 0 : lane>>4; // lane<64
  quad = lane >> 4;
  int n = blockIdx.x*16 + l15;
  int mbase = blockIdx.y*64;
  floatx4 z = {0.f,0.f,0.f,0.f};
  floatx4 acc[4];
#pragma unroll
  for (int t=0;t<4;++t) acc[t]=z;
  for (int k0=0;k0<2048;k0+=32) {
    int k = k0 + quad*8;
    const float* wp = W_out + (size_t)n*2048 + k;
    float4 w0=*(const float4*)wp, w1=*(const float4*)(wp+4);
    short8 bfrag = cvt8(w0,w1);
#pragma unroll
    for (int t=0;t<4;++t) {
      short8 afrag = *(const short8*)(ctxh + (mbase + t*16 + l15)*2048 + k);
      acc[t] = mfma16(afrag, bfrag, acc[t]);
    }
  }
  float bias = b_out[n];
#pragma unroll
  for (int t=0;t<4;++t)
#pragma unroll
    for (int r=0;r<4;++r) {
      int m = mbase + t*16 + quad*4 + r;
      av[m*Hn + n] = f2bf_bits(tanhf(acc[t][r] + bias));
    }
}

// K6a: logits[128][50000] = av @ W_out2^T + b_out2 (bf16 MFMA, fp32 out into d_out)
__global__ void __launch_bounds__(64) k6a_logits(const unsigned short* __restrict__ av,
    const float* __restrict__ W2, const float* __restrict__ b2,
    float* __restrict__ out) {
  int lane = threadIdx.x, l15 = lane&15, quad = lane>>4;
  int v = blockIdx.x*16 + l15;
  floatx4 z = {0.f,0.f,0.f,0.f};
  floatx4 acc[8];
#pragma unroll
  for (int t=0;t<8;++t) acc[t]=z;
  for (int k0=0;k0<1024;k0+=32) {
    int k = k0 + quad*8;
    const float* wp = W2 + (size_t)v*Hn + k;
    float4 w0=*(const float4*)wp, w1=*(const float4*)(wp+4);
    short8 bfrag = cvt8(w0,w1);
#pragma unroll
    for (int t=0;t<8;++t) {
      short8 afrag = *(const short8*)(av + (t*16 + l15)*Hn + k);
      acc[t] = mfma16(afrag, bfrag, acc[t]);
    }
  }
  float bias = b2[v];
#pragma unroll
  for (int t=0;t<8;++t)
#pragma unroll
    for (int r=0;r<4;++r) {
      int m = t*16 + quad*4 + r;
      out[(size_t)m*Vn + v] = acc[t][r] + bias;
    }
}

// K6b: per-row logsumexp over V
__global__ void __launch_bounds__(256) k6b_lse(const float* __restrict__ logits,
    float* __restrict__ lse) {
  int b = blockIdx.x, tid = threadIdx.x;
  const float* row = logits + (size_t)b*Vn;
  float m = -3.4e38f, s = 0.f;
  for (int v = tid; v < Vn; v += 256) {
    float x = row[v];
    float nm = fmaxf(m, x);
    s = s*expf(m-nm) + expf(x-nm);
    m = nm;
  }
  __shared__ float sm[256], ss[256];
  sm[tid]=m; ss[tid]=s;
  __syncthreads();
  for (int st=128; st>0; st>>=1) {
    if (tid<st) {
      float m1=sm[tid], m2=sm[tid+st];
      float nm=fmaxf(m1,m2);
      ss[tid]=ss[tid]*expf(m1-nm)+ss[tid+st]*expf(m2-nm);
      sm[tid]=nm;
    }
    __syncthreads();
  }
  if (tid==0) lse[b] = sm[0] + logf(ss[0]);
}

// K6c: out = logits - lse[b], in place, float4
__global__ void __launch_bounds__(256) k6c_sub(float* __restrict__ out,
    const float* __restrict__ lse) {
  int f = blockIdx.x*256 + threadIdx.x;
  if (f >= 12500) return;
  int b = blockIdx.y;
  float l = lse[b];
  float4* p = (float4*)(out + (size_t)b*Vn) + f;
  float4 v = *p;
  v.x -= l; v.y -= l; v.z -= l; v.w -= l;
  *p = v;
}

extern "C" void kernel_launch(void* const* d_in, const int* in_sizes, int n_in,
                              void* d_out, int out_size, void* d_ws, size_t ws_size,
                              hipStream_t stream) {
  const int*   inp    = (const int*)d_in[0];
  const float* prev_h = (const float*)d_in[1];
  const float* prev_c = (const float*)d_in[2];
  const float* enc    = (const float*)d_in[3];
  const float* emb    = (const float*)d_in[4];
  const float* W_ih   = (const float*)d_in[5];
  const float* W_hh   = (const float*)d_in[6];
  const float* b_ih   = (const float*)d_in[7];
  const float* b_hh   = (const float*)d_in[8];
  const float* W_out  = (const float*)d_in[9];
  const float* b_out  = (const float*)d_in[10];
  const float* W_out2 = (const float*)d_in[11];
  const float* b_out2 = (const float*)d_in[12];
  float* out = (float*)d_out;
  char* ws = (char*)d_ws;

  unsigned short* xh_hi = (unsigned short*)(ws + 0);        // 512 KB
  unsigned short* xh_lo = (unsigned short*)(ws + 524288);   // 256 KB
  float* gates          = (float*)(ws + 786432);            // 2 MB
  float* h32            = (float*)(ws + 2883584);           // 512 KB
  float* scores         = (float*)(ws + 3407872);           // 64 KB
  unsigned short* ctxh  = (unsigned short*)(ws + 3473408);  // 512 KB
  unsigned short* av    = (unsigned short*)(ws + 3997696);  // 256 KB
  float* lse            = (float*)(ws + 4259840);           // 512 B

  k1_pack   <<<1024, 256, 0, stream>>>(inp, prev_h, emb, xh_hi, xh_lo);
  k2_gates  <<<256, 64, 0, stream>>>(xh_hi, xh_lo, W_ih, W_hh, b_ih, b_hh, gates);
  k3_lstm   <<<512, 256, 0, stream>>>(gates, prev_c, out, h32, ctxh);
  k4a_scores<<<4096, 256, 0, stream>>>(enc, h32, scores);
  k4b_ctx   <<<dim3(4,128), 256, 0, stream>>>(enc, scores, ctxh);
  k5_att    <<<dim3(64,2), 64, 0, stream>>>(ctxh, W_out, b_out, av);
  k6a_logits<<<3125, 64, 0, stream>>>(av, W_out2, b_out2, out);
  k6b_lse   <<<128, 256, 0, stream>>>(out, lse);
  k6c_sub   <<<dim3(49,128), 256, 0, stream>>>(out, lse);
}

// Round 2
// 628.692 us; speedup vs baseline: 1.1945x; 1.1945x over previous
//
#include <hip/hip_runtime.h>
#include <hip/hip_bf16.h>
#include <math.h>

#define Bn 128
#define Sn 128
#define Hn 1024
#define Vn 50000

using short8  = __attribute__((ext_vector_type(8))) short;
using floatx4 = __attribute__((ext_vector_type(4))) float;

__device__ __forceinline__ unsigned short f2bf_bits(float f) {
  union { __hip_bfloat16 h; unsigned short u; } cv;
  cv.h = __float2bfloat16(f);
  return cv.u;
}
__device__ __forceinline__ float bf_bits2f(unsigned short u) {
  union { __hip_bfloat16 h; unsigned short u; } cv;
  cv.u = u;
  return __bfloat162float(cv.h);
}
__device__ __forceinline__ short8 cvt8(float4 a, float4 b) {
  short8 r;
  r[0]=(short)f2bf_bits(a.x); r[1]=(short)f2bf_bits(a.y);
  r[2]=(short)f2bf_bits(a.z); r[3]=(short)f2bf_bits(a.w);
  r[4]=(short)f2bf_bits(b.x); r[5]=(short)f2bf_bits(b.y);
  r[6]=(short)f2bf_bits(b.z); r[7]=(short)f2bf_bits(b.w);
  return r;
}
__device__ __forceinline__ void split8(float4 a, float4 b, short8& hi, short8& lo) {
  float f[8] = {a.x,a.y,a.z,a.w,b.x,b.y,b.z,b.w};
#pragma unroll
  for (int i=0;i<8;++i) {
    unsigned short h = f2bf_bits(f[i]);
    hi[i] = (short)h;
    lo[i] = (short)f2bf_bits(f[i] - bf_bits2f(h));
  }
}
__device__ __forceinline__ floatx4 mfma16(short8 a, short8 b, floatx4 c) {
  return __builtin_amdgcn_mfma_f32_16x16x32_bf16(a, b, c, 0, 0, 0);
}

// K1: pack A matrix for LSTM GEMM
__global__ void __launch_bounds__(256) k1_pack(const int* __restrict__ inp,
    const float* __restrict__ prev_h, const float* __restrict__ emb,
    unsigned short* __restrict__ xh_hi, unsigned short* __restrict__ xh_lo) {
  int idx = blockIdx.x*256 + threadIdx.x;
  int b = idx >> 11, k = idx & 2047;
  if (k < 1024) {
    float v = emb[(size_t)inp[b]*Hn + k];
    xh_hi[idx] = f2bf_bits(v);
  } else {
    float v = prev_h[b*Hn + (k-1024)];
    unsigned short hi = f2bf_bits(v);
    xh_hi[idx] = hi;
    xh_lo[b*Hn + (k-1024)] = f2bf_bits(v - bf_bits2f(hi));
  }
}

// K2: gates = x@W_ih^T + prev_h@W_hh^T + biases. M-split x8 -> 2048 waves.
__global__ void __launch_bounds__(64) k2_gates(
    const unsigned short* __restrict__ xh_hi, const unsigned short* __restrict__ xh_lo,
    const float* __restrict__ W_ih, const float* __restrict__ W_hh,
    const float* __restrict__ b_ih, const float* __restrict__ b_hh,
    float* __restrict__ gates) {
  int lane = threadIdx.x, l15 = lane & 15, quad = lane >> 4;
  int n = blockIdx.x*16 + l15;
  int mt = blockIdx.y;                      // 0..7 -> rows mt*16..mt*16+15
  floatx4 acc = {0.f,0.f,0.f,0.f};

  // half 0: x @ W_ih^T, plain bf16
  for (int k0 = 0; k0 < 1024; k0 += 32) {
    int k = k0 + quad*8;
    const float* wp = W_ih + (size_t)n*Hn + k;
    float4 w0 = *(const float4*)wp;
    float4 w1 = *(const float4*)(wp+4);
    short8 bfrag = cvt8(w0,w1);
    short8 afrag = *(const short8*)(xh_hi + (mt*16 + l15)*2048 + k);
    acc = mfma16(afrag, bfrag, acc);
  }
  // half 1: prev_h @ W_hh^T, split hi/lo
  for (int k0 = 0; k0 < 1024; k0 += 32) {
    int k = k0 + quad*8;
    const float* wp = W_hh + (size_t)n*Hn + k;
    float4 w0 = *(const float4*)wp;
    float4 w1 = *(const float4*)(wp+4);
    short8 whi, wlo; split8(w0,w1,whi,wlo);
    short8 ahi = *(const short8*)(xh_hi + (mt*16 + l15)*2048 + 1024 + k);
    short8 alo = *(const short8*)(xh_lo + (mt*16 + l15)*1024 + k);
    acc = mfma16(ahi, whi, acc);
    acc = mfma16(alo, whi, acc);
    acc = mfma16(ahi, wlo, acc);
  }
  float bias = b_ih[n] + b_hh[n];
#pragma unroll
  for (int r=0;r<4;++r) {
    int m = mt*16 + quad*4 + r;
    gates[m*4096 + n] = acc[r] + bias;
  }
}

// K3: LSTM elementwise
__global__ void __launch_bounds__(256) k3_lstm(const float* __restrict__ gates,
    const float* __restrict__ prev_c, float* __restrict__ out,
    float* __restrict__ h32, unsigned short* __restrict__ ctxh) {
  int idx = blockIdx.x*256 + threadIdx.x;
  int b = idx >> 10, k = idx & 1023;
  const float* g = gates + b*4096;
  float gi = g[k], gf = g[k+1024], gg = g[k+2048], go = g[k+3072];
  float si = 1.f/(1.f+expf(-gi));
  float sf = 1.f/(1.f+expf(-gf));
  float so = 1.f/(1.f+expf(-go));
  float c = sf*prev_c[idx] + si*tanhf(gg);
  float h = so*tanhf(c);
  out[6400000 + idx] = h;
  out[6531072 + idx] = c;
  h32[idx] = h;
  ctxh[b*2048 + 1024 + k] = f2bf_bits(h);
}

// K4a: scores
__global__ void __launch_bounds__(256) k4a_scores(const float* __restrict__ enc,
    const float* __restrict__ h32, float* __restrict__ scores) {
  int w = blockIdx.x*4 + (threadIdx.x>>6);
  int lane = threadIdx.x & 63;
  int b = w >> 7, s = w & 127;
  const float* e = enc + (size_t)(b*Sn + s)*Hn;
  const float* hp = h32 + b*Hn;
  float sum = 0.f;
#pragma unroll
  for (int j=0;j<4;++j) {
    int k = j*256 + lane*4;
    float4 ev = *(const float4*)(e+k);
    float4 hv = *(const float4*)(hp+k);
    sum += ev.x*hv.x + ev.y*hv.y + ev.z*hv.z + ev.w*hv.w;
  }
#pragma unroll
  for (int o=32;o>0;o>>=1) sum += __shfl_xor(sum, o, 64);
  if (lane==0) {
    if (sum == 0.f) sum = -1e11f;
    scores[b*Sn+s] = sum;
  }
}

// K4b: softmax over S + context accumulate
__global__ void __launch_bounds__(256) k4b_ctx(const float* __restrict__ enc,
    const float* __restrict__ scores, unsigned short* __restrict__ ctxh) {
  __shared__ float sc[128];
  __shared__ float red[128];
  int tid = threadIdx.x, b = blockIdx.y;
  if (tid < 128) { float v = scores[b*Sn+tid]; sc[tid] = v; red[tid] = v; }
  __syncthreads();
  for (int st=64; st>0; st>>=1) {
    if (tid<st) red[tid] = fmaxf(red[tid], red[tid+st]);
    __syncthreads();
  }
  float mx = red[0];
  __syncthreads();
  if (tid<128) { float e = expf(sc[tid]-mx); sc[tid]=e; red[tid]=e; }
  __syncthreads();
  for (int st=64; st>0; st>>=1) {
    if (tid<st) red[tid] += red[tid+st];
    __syncthreads();
  }
  float inv = 1.0f/red[0];
  __syncthreads();
  if (tid<128) sc[tid] *= inv;
  __syncthreads();
  int hcol = blockIdx.x*256 + tid;
  const float* e = enc + (size_t)b*(Sn*Hn) + hcol;
  float acc = 0.f;
#pragma unroll 8
  for (int s2=0; s2<128; ++s2) acc += sc[s2]*e[(size_t)s2*Hn];
  ctxh[b*2048 + hcol] = f2bf_bits(acc);
}

// K5: av = tanh([ctx,h] @ W_out^T + b_out). M-split x8 -> 512 waves.
__global__ void __launch_bounds__(64) k5_att(const unsigned short* __restrict__ ctxh,
    const float* __restrict__ W_out, const float* __restrict__ b_out,
    unsigned short* __restrict__ av) {
  int lane = threadIdx.x, l15 = lane&15, quad = lane>>4;
  int n = blockIdx.x*16 + l15;
  int mt = blockIdx.y;                      // 0..7
  floatx4 acc = {0.f,0.f,0.f,0.f};
  for (int k0=0;k0<2048;k0+=32) {
    int k = k0 + quad*8;
    const float* wp = W_out + (size_t)n*2048 + k;
    float4 w0=*(const float4*)wp, w1=*(const float4*)(wp+4);
    short8 bfrag = cvt8(w0,w1);
    short8 afrag = *(const short8*)(ctxh + (mt*16 + l15)*2048 + k);
    acc = mfma16(afrag, bfrag, acc);
  }
  float bias = b_out[n];
#pragma unroll
  for (int r=0;r<4;++r) {
    int m = mt*16 + quad*4 + r;
    av[m*Hn + n] = f2bf_bits(tanhf(acc[r] + bias));
  }
}

// K6a v2: logits = av @ W2^T + b2. 256-thr blocks, 128x64 tile,
// double-buffered LDS staging of both av-tile and W2-tile.
__global__ void __launch_bounds__(256) k6a_logits(const unsigned short* __restrict__ av,
    const float* __restrict__ W2, const float* __restrict__ b2,
    float* __restrict__ out) {
  // LDS: rows padded to 40 ushorts (80 B) -> 2-way bank aliasing only (free)
  __shared__ unsigned short lA[2][128*40];   // 2 x 10240 B
  __shared__ unsigned short lB[2][64*40];    // 2 x 5120 B
  int tid = threadIdx.x;
  int wave = tid>>6, lane = tid&63, l15 = lane&15, quad = lane>>4;
  int tileN = blockIdx.x*64;

  // staging roles
  int arow = tid>>2, apart = tid&3;   // av rows: arow, arow+64; 16B parts
  int brow = tid>>3, bpart = tid&7;   // W2 rows: brow, brow+32; 16B fp32 parts

  uint4 aR0, aR1; float4 wR0, wR1;

  auto gload = [&](int k0) {
    aR0 = *(const uint4*)(av + (size_t)arow*Hn + k0 + apart*8);
    aR1 = *(const uint4*)(av + (size_t)(arow+64)*Hn + k0 + apart*8);
    int r0 = tileN + brow;      if (r0 > Vn-1) r0 = Vn-1;
    int r1 = tileN + brow + 32; if (r1 > Vn-1) r1 = Vn-1;
    wR0 = *(const float4*)(W2 + (size_t)r0*Hn + k0 + bpart*4);
    wR1 = *(const float4*)(W2 + (size_t)r1*Hn + k0 + bpart*4);
  };
  auto lstore = [&](int buf) {
    *(uint4*)(&lA[buf][arow*40 + apart*8])      = aR0;
    *(uint4*)(&lA[buf][(arow+64)*40 + apart*8]) = aR1;
    ushort4 p0, p1;
    p0.x=f2bf_bits(wR0.x); p0.y=f2bf_bits(wR0.y); p0.z=f2bf_bits(wR0.z); p0.w=f2bf_bits(wR0.w);
    p1.x=f2bf_bits(wR1.x); p1.y=f2bf_bits(wR1.y); p1.z=f2bf_bits(wR1.z); p1.w=f2bf_bits(wR1.w);
    *(ushort4*)(&lB[buf][brow*40 + bpart*4])      = p0;
    *(ushort4*)(&lB[buf][(brow+32)*40 + bpart*4]) = p1;
  };

  floatx4 z = {0.f,0.f,0.f,0.f};
  floatx4 acc[8];
#pragma unroll
  for (int t=0;t<8;++t) acc[t]=z;

  gload(0);
  lstore(0);
  __syncthreads();

  for (int kc=0; kc<32; ++kc) {
    int cur = kc&1;
    if (kc<31) gload((kc+1)*32);
    short8 bfrag = *(const short8*)(&lB[cur][(wave*16+l15)*40 + quad*8]);
    short8 af[8];
#pragma unroll
    for (int t=0;t<8;++t)
      af[t] = *(const short8*)(&lA[cur][(t*16+l15)*40 + quad*8]);
#pragma unroll
    for (int t=0;t<8;++t)
      acc[t] = mfma16(af[t], bfrag, acc[t]);
    if (kc<31) {
      __syncthreads();
      lstore(1-cur);
      __syncthreads();
    }
  }

  int n = tileN + wave*16 + l15;
  if (n < Vn) {
    float bias = b2[n];
#pragma unroll
    for (int t=0;t<8;++t)
#pragma unroll
      for (int r=0;r<4;++r) {
        int m = t*16 + quad*4 + r;
        out[(size_t)m*Vn + n] = acc[t][r] + bias;
      }
  }
}

// K6b1: partial logsumexp over 8 V-chunks per row
__global__ void __launch_bounds__(256) k6b1_lse(const float* __restrict__ logits,
    float* __restrict__ pm, float* __restrict__ ps) {
  int b = blockIdx.y, c = blockIdx.x, tid = threadIdx.x;
  int v0 = c*6250, v1 = v0 + 6250;
  const float* row = logits + (size_t)b*Vn;
  float m = -3.4e38f, s = 0.f;
  for (int v = v0 + tid; v < v1; v += 256) {
    float x = row[v];
    float nm = fmaxf(m, x);
    s = s*expf(m-nm) + expf(x-nm);
    m = nm;
  }
  __shared__ float sm[256], ss[256];
  sm[tid]=m; ss[tid]=s;
  __syncthreads();
  for (int st=128; st>0; st>>=1) {
    if (tid<st) {
      float m1=sm[tid], m2=sm[tid+st];
      float nm=fmaxf(m1,m2);
      ss[tid]=ss[tid]*expf(m1-nm)+ss[tid+st]*expf(m2-nm);
      sm[tid]=nm;
    }
    __syncthreads();
  }
  if (tid==0) { pm[b*8+c]=sm[0]; ps[b*8+c]=ss[0]; }
}

// K6b2: combine partials -> lse[b]
__global__ void __launch_bounds__(128) k6b2_lse(const float* __restrict__ pm,
    const float* __restrict__ ps, float* __restrict__ lse) {
  int b = threadIdx.x;
  float m = -3.4e38f, s = 0.f;
#pragma unroll
  for (int c=0;c<8;++c) {
    float m2 = pm[b*8+c], s2 = ps[b*8+c];
    float nm = fmaxf(m, m2);
    s = s*expf(m-nm) + s2*expf(m2-nm);
    m = nm;
  }
  lse[b] = m + logf(s);
}

// K6c: out = logits - lse[b], in place, float4
__global__ void __launch_bounds__(256) k6c_sub(float* __restrict__ out,
    const float* __restrict__ lse) {
  int f = blockIdx.x*256 + threadIdx.x;
  if (f >= 12500) return;
  int b = blockIdx.y;
  float l = lse[b];
  float4* p = (float4*)(out + (size_t)b*Vn) + f;
  float4 v = *p;
  v.x -= l; v.y -= l; v.z -= l; v.w -= l;
  *p = v;
}

extern "C" void kernel_launch(void* const* d_in, const int* in_sizes, int n_in,
                              void* d_out, int out_size, void* d_ws, size_t ws_size,
                              hipStream_t stream) {
  const int*   inp    = (const int*)d_in[0];
  const float* prev_h = (const float*)d_in[1];
  const float* prev_c = (const float*)d_in[2];
  const float* enc    = (const float*)d_in[3];
  const float* emb    = (const float*)d_in[4];
  const float* W_ih   = (const float*)d_in[5];
  const float* W_hh   = (const float*)d_in[6];
  const float* b_ih   = (const float*)d_in[7];
  const float* b_hh   = (const float*)d_in[8];
  const float* W_out  = (const float*)d_in[9];
  const float* b_out  = (const float*)d_in[10];
  const float* W_out2 = (const float*)d_in[11];
  const float* b_out2 = (const float*)d_in[12];
  float* out = (float*)d_out;
  char* ws = (char*)d_ws;

  unsigned short* xh_hi = (unsigned short*)(ws + 0);        // 512 KB
  unsigned short* xh_lo = (unsigned short*)(ws + 524288);   // 256 KB
  float* gates          = (float*)(ws + 786432);            // 2 MB
  float* h32            = (float*)(ws + 2883584);           // 512 KB
  float* scores         = (float*)(ws + 3407872);           // 64 KB
  unsigned short* ctxh  = (unsigned short*)(ws + 3473408);  // 512 KB
  unsigned short* av    = (unsigned short*)(ws + 3997696);  // 256 KB
  float* lse            = (float*)(ws + 4259840);           // 512 B
  float* pm             = (float*)(ws + 4260352);           // 4 KB
  float* ps             = (float*)(ws + 4264448);           // 4 KB

  k1_pack   <<<1024, 256, 0, stream>>>(inp, prev_h, emb, xh_hi, xh_lo);
  k2_gates  <<<dim3(256,8), 64, 0, stream>>>(xh_hi, xh_lo, W_ih, W_hh, b_ih, b_hh, gates);
  k3_lstm   <<<512, 256, 0, stream>>>(gates, prev_c, out, h32, ctxh);
  k4a_scores<<<4096, 256, 0, stream>>>(enc, h32, scores);
  k4b_ctx   <<<dim3(4,128), 256, 0, stream>>>(enc, scores, ctxh);
  k5_att    <<<dim3(64,8), 64, 0, stream>>>(ctxh, W_out, b_out, av);
  k6a_logits<<<782, 256, 0, stream>>>(av, W_out2, b_out2, out);
  k6b1_lse  <<<dim3(8,128), 256, 0, stream>>>(out, pm, ps);
  k6b2_lse  <<<1, 128, 0, stream>>>(pm, ps, lse);
  k6c_sub   <<<dim3(49,128), 256, 0, stream>>>(out, lse);
}